// Round 1
// baseline (26.549 us; speedup 1.0000x reference)
//
#include <hip/hip_runtime.h>

#define D_MODEL 256
#define SPECIAL_OFFSET 68      // 52 cards + 16 bet bins
#define NUM_SPECIAL 8
#define NUM_CONTEXT 16
#define LN_EPS 1e-5f

// One 64-lane wave per token. Each lane owns 4 consecutive output channels
// (float4). token_id is wave-uniform -> branches are wave-uniform (no
// divergence). Block = 256 threads = 4 waves = 4 tokens.
__global__ __launch_bounds__(256) void ctx_emb_kernel(
    const int*   __restrict__ token_ids,        // [N]
    const float* __restrict__ context_features, // [N, 16]
    const float* __restrict__ special_table,    // [8, 256]
    const float* __restrict__ cls_w,            // [3, 256]
    const float* __restrict__ cls_b,            // [256]
    const float* __restrict__ cls_g,            // [256]
    const float* __restrict__ cls_be,           // [256]
    const float* __restrict__ ctx_w,            // [16, 256]
    const float* __restrict__ ctx_b,            // [256]
    const float* __restrict__ ctx_g,            // [256]
    const float* __restrict__ ctx_be,           // [256]
    float*       __restrict__ out,              // [N, 256]
    int n_tokens)
{
    const int wave = (int)((blockIdx.x * (unsigned)blockDim.x + threadIdx.x) >> 6);
    const int lane = threadIdx.x & 63;
    if (wave >= n_tokens) return;

    const int tid = token_ids[wave];   // same address for all 64 lanes -> broadcast
    const int d0  = lane * 4;

    float4 acc = make_float4(0.f, 0.f, 0.f, 0.f);

    // Special-token embedding (includes tokens 68 and 69!)
    if (tid >= SPECIAL_OFFSET && tid < SPECIAL_OFFSET + NUM_SPECIAL) {
        acc = *(const float4*)(special_table + (tid - SPECIAL_OFFSET) * D_MODEL + d0);
    }

    const bool is_cls = (tid == SPECIAL_OFFSET);       // CLS = +0
    const bool is_ctx = (tid == SPECIAL_OFFSET + 1);   // CONTEXT = +1

    if (is_cls || is_ctx) {
        const float* w  = is_cls ? cls_w  : ctx_w;
        const float* bb = is_cls ? cls_b  : ctx_b;
        const float* g  = is_cls ? cls_g  : ctx_g;
        const float* be = is_cls ? cls_be : ctx_be;
        const int    K  = is_cls ? 3 : NUM_CONTEXT;

        const float* f = context_features + (size_t)wave * NUM_CONTEXT;

        // h = f[0:K] @ w + bb  (each lane computes 4 output channels)
        float4 h = *(const float4*)(bb + d0);
        #pragma unroll 4
        for (int k = 0; k < K; ++k) {
            const float  fk = f[k];
            const float4 wk = *(const float4*)(w + k * D_MODEL + d0);
            h.x = fmaf(fk, wk.x, h.x);
            h.y = fmaf(fk, wk.y, h.y);
            h.z = fmaf(fk, wk.z, h.z);
            h.w = fmaf(fk, wk.w, h.w);
        }

        // LayerNorm over 256 channels: wave-wide sum / sumsq butterfly
        float s  = h.x + h.y + h.z + h.w;
        float sq = h.x * h.x + h.y * h.y + h.z * h.z + h.w * h.w;
        #pragma unroll
        for (int m = 1; m < 64; m <<= 1) {
            s  += __shfl_xor(s,  m, 64);
            sq += __shfl_xor(sq, m, 64);
        }
        const float mu  = s * (1.0f / D_MODEL);
        const float var = sq * (1.0f / D_MODEL) - mu * mu;
        const float rs  = rsqrtf(var + LN_EPS);

        const float4 gv = *(const float4*)(g  + d0);
        const float4 bv = *(const float4*)(be + d0);
        acc.x += fmaxf((h.x - mu) * rs * gv.x + bv.x, 0.f);
        acc.y += fmaxf((h.y - mu) * rs * gv.y + bv.y, 0.f);
        acc.z += fmaxf((h.z - mu) * rs * gv.z + bv.z, 0.f);
        acc.w += fmaxf((h.w - mu) * rs * gv.w + bv.w, 0.f);
    }

    *(float4*)(out + (size_t)wave * D_MODEL + d0) = acc;
}

extern "C" void kernel_launch(void* const* d_in, const int* in_sizes, int n_in,
                              void* d_out, int out_size, void* d_ws, size_t ws_size,
                              hipStream_t stream) {
    const int*   token_ids = (const int*)  d_in[0];
    const float* ctx_feat  = (const float*)d_in[1];
    const float* special   = (const float*)d_in[2];
    const float* cls_w     = (const float*)d_in[3];
    const float* cls_b     = (const float*)d_in[4];
    const float* cls_g     = (const float*)d_in[5];
    const float* cls_be    = (const float*)d_in[6];
    const float* ctx_w     = (const float*)d_in[7];
    const float* ctx_b     = (const float*)d_in[8];
    const float* ctx_g     = (const float*)d_in[9];
    const float* ctx_be    = (const float*)d_in[10];
    float*       out       = (float*)d_out;

    const int n_tokens = in_sizes[0];            // B*S = 131072
    const int waves_per_block = 256 / 64;        // 4 tokens per block
    const int grid = (n_tokens + waves_per_block - 1) / waves_per_block;

    ctx_emb_kernel<<<grid, 256, 0, stream>>>(
        token_ids, ctx_feat, special,
        cls_w, cls_b, cls_g, cls_be,
        ctx_w, ctx_b, ctx_g, ctx_be,
        out, n_tokens);
}